// Round 16
// baseline (310.237 us; speedup 1.0000x reference)
//
#include <hip/hip_runtime.h>
#include <float.h>

#define EPS 1e-5f
#define FMA4(A_, W_, T_) { (A_).x += (W_)*(T_).x; (A_).y += (W_)*(T_).y; (A_).z += (W_)*(T_).z; (A_).w += (W_)*(T_).w; }

// ---------------- K0: pad w1 (256x61) -> w1p (256x64, zero-padded cols) ----------------
__global__ __launch_bounds__(256) void k0_prep(const float* __restrict__ w1, float* __restrict__ w1p) {
    int i = blockIdx.x * 256 + threadIdx.x;
    if (i < 16384) {
        int o = i >> 6, c = i & 63;
        w1p[i] = (c < 61) ? w1[o * 61 + c] : 0.f;
    }
}

// ---------------- K1: max over last dim: (32,512,2048) -> (32*512) ----------------
__global__ __launch_bounds__(256) void k1_maxpool(const float* __restrict__ gf, float* __restrict__ gfeat) {
    int row = blockIdx.x * 4 + (threadIdx.x >> 6);   // one wave per row
    int lane = threadIdx.x & 63;
    const float4* p = (const float4*)(gf + (size_t)row * 2048);
    float m = -FLT_MAX;
#pragma unroll
    for (int w = 0; w < 8; ++w) {
        float4 v = p[lane + (w << 6)];
        m = fmaxf(m, fmaxf(fmaxf(v.x, v.y), fmaxf(v.z, v.w)));
    }
#pragma unroll
    for (int off = 32; off >= 1; off >>= 1) m = fmaxf(m, __shfl_xor(m, off));
    if (lane == 0) gfeat[row] = m;
}

// ---------------- K2: tok = relu(bn(gfeat @ token_w^T + token_b)) : (32,65536) ----------------
__global__ __launch_bounds__(256) void k2_token(
    const float* __restrict__ gfeat, const float* __restrict__ tw, const float* __restrict__ tbias,
    const float* __restrict__ bg, const float* __restrict__ bb,
    const float* __restrict__ bm, const float* __restrict__ bv,
    float* __restrict__ tok) {
    __shared__ __align__(16) float wl[128 * 33];
    __shared__ __align__(16) float gl[32 * 36];
    int tid = threadIdx.x;
    int t0 = blockIdx.x * 128;
    int tx = tid & 7, ty = tid >> 3;
    float4 acc[4];
#pragma unroll
    for (int i = 0; i < 4; ++i) acc[i] = make_float4(0.f, 0.f, 0.f, 0.f);
    for (int k0 = 0; k0 < 512; k0 += 32) {
        if (k0) __syncthreads();
        {
            int r = tid >> 1, h = tid & 1;
            const float* src = tw + (size_t)(t0 + r) * 512 + k0 + h * 16;
            float* dst = wl + r * 33 + h * 16;
#pragma unroll
            for (int q = 0; q < 4; ++q) {
                float4 x = *(const float4*)(src + q * 4);
                dst[q*4+0] = x.x; dst[q*4+1] = x.y; dst[q*4+2] = x.z; dst[q*4+3] = x.w;
            }
            int bq = tid >> 3, kq = tid & 7;
            float4 gx = *(const float4*)(gfeat + bq * 512 + k0 + kq * 4);
            gl[(kq*4+0)*36 + bq] = gx.x;
            gl[(kq*4+1)*36 + bq] = gx.y;
            gl[(kq*4+2)*36 + bq] = gx.z;
            gl[(kq*4+3)*36 + bq] = gx.w;
        }
        __syncthreads();
#pragma unroll
        for (int kk = 0; kk < 32; ++kk) {
            float4 g4 = *(const float4*)(gl + kk * 36 + tx * 4);
#pragma unroll
            for (int i = 0; i < 4; ++i) {
                float a = wl[(ty * 4 + i) * 33 + kk];
                FMA4(acc[i], a, g4);
            }
        }
    }
#pragma unroll
    for (int i = 0; i < 4; ++i) {
        int t = t0 + ty * 4 + i;
        float scale = bg[t] * rsqrtf(bv[t] + EPS);
        float sh = (tbias[t] - bm[t]) * scale + bb[t];
        tok[(size_t)(tx*4+0) * 65536 + t] = fmaxf(acc[i].x * scale + sh, 0.f);
        tok[(size_t)(tx*4+1) * 65536 + t] = fmaxf(acc[i].y * scale + sh, 0.f);
        tok[(size_t)(tx*4+2) * 65536 + t] = fmaxf(acc[i].z * scale + sh, 0.f);
        tok[(size_t)(tx*4+3) * 65536 + t] = fmaxf(acc[i].w * scale + sh, 0.f);
    }
}

// ---------------- K3: fused q,k,v projections -> padded [b][n][128] buffers ----------------
// grid (16 ntiles of 64 n, 32 b), 384 threads (6 waves). Thread = (m = tid/128
// in {q,k,v} — wave-uniform, o = tid&127). Each thread holds ONE 16-float4
// weight row in registers (no spill) and loops all 64 columns.
__global__ __launch_bounds__(384) void k3_qkv(
    const float* __restrict__ tok,
    const float* __restrict__ qw, const float* __restrict__ kw, const float* __restrict__ vw,
    const float* __restrict__ qg, const float* __restrict__ qb, const float* __restrict__ qm, const float* __restrict__ qv,
    const float* __restrict__ kg, const float* __restrict__ kb, const float* __restrict__ km, const float* __restrict__ kvv,
    const float* __restrict__ vg, const float* __restrict__ vb, const float* __restrict__ vm, const float* __restrict__ vvv,
    float* __restrict__ qbuf, float* __restrict__ kbuf, float* __restrict__ vbuf) {
    __shared__ __align__(16) float tokt[64 * 68];    // [n][c]
    int tid = threadIdx.x;
    int b = blockIdx.y;
    int n0 = blockIdx.x << 6;
    for (int i = tid; i < 1024; i += 384) {
        int c = i >> 4, q4 = i & 15;
        float4 x = *(const float4*)(tok + (size_t)b * 65536 + c * 1024 + n0 + q4 * 4);
        tokt[(q4*4+0)*68 + c] = x.x;
        tokt[(q4*4+1)*68 + c] = x.y;
        tokt[(q4*4+2)*68 + c] = x.z;
        tokt[(q4*4+3)*68 + c] = x.w;
    }
    int m = tid / 128;                 // 0:q 1:k 2:v (wave-uniform: 128 = 2 waves)
    int o = tid & 127;
    bool valid = (o < 122);
    const float* wsrc = (m == 0) ? qw : ((m == 1) ? kw : vw);
    const float* pg   = (m == 0) ? qg : ((m == 1) ? kg : vg);
    const float* pb   = (m == 0) ? qb : ((m == 1) ? kb : vb);
    const float* pm   = (m == 0) ? qm : ((m == 1) ? km : vm);
    const float* pv   = (m == 0) ? qv : ((m == 1) ? kvv : vvv);
    float* dst        = (m == 0) ? qbuf : ((m == 1) ? kbuf : vbuf);
    float scl = 0.f, shf = 0.f;
    if (valid) {
        float s = pg[o] * rsqrtf(pv[o] + EPS);
        scl = s; shf = pb[o] - pm[o] * s;
    }
    float4 wreg[16];
    {
        const float* wr = wsrc + o * 64;
#pragma unroll
        for (int c4 = 0; c4 < 16; ++c4)
            wreg[c4] = valid ? *(const float4*)(wr + c4 * 4) : make_float4(0.f,0.f,0.f,0.f);
    }
    __syncthreads();
    for (int nn = 0; nn < 64; ++nn) {
        const float* t = tokt + nn * 68;
        float s = 0.f;
#pragma unroll
        for (int c4 = 0; c4 < 16; ++c4) {
            float4 tv = *(const float4*)(t + c4 * 4);
            s += wreg[c4].x*tv.x + wreg[c4].y*tv.y + wreg[c4].z*tv.z + wreg[c4].w*tv.w;
        }
        dst[((size_t)b * 1024 + n0 + nn) * 128 + o] = fmaxf(s * scl + shf, 0.f);
    }
}

// ---------------- K4: S partials — pure outer-product GEMM over n ----------------
__global__ __launch_bounds__(256) void k4_s(
    const float* __restrict__ kbuf, const float* __restrict__ vbuf,
    float* __restrict__ sp) {
    __shared__ __align__(16) float kl[32 * 128];
    __shared__ __align__(16) float vl[32 * 128];
    int tid = threadIdx.x;
    int b = blockIdx.y, ns = blockIdx.x;
    int tx = tid & 15, ty = tid >> 4;
    float acc[8][8];
#pragma unroll
    for (int i = 0; i < 8; ++i)
#pragma unroll
        for (int j = 0; j < 8; ++j) acc[i][j] = 0.f;
    for (int chunk = 0; chunk < 2; ++chunk) {
        int nb = (ns << 6) + (chunk << 5);
        if (chunk) __syncthreads();
        for (int i = tid; i < 1024; i += 256) {
            int n = i >> 5, q = i & 31;
            size_t src = ((size_t)b * 1024 + nb + n) * 128 + q * 4;
            *(float4*)(kl + n * 128 + q * 4) = *(const float4*)(kbuf + src);
            *(float4*)(vl + n * 128 + q * 4) = *(const float4*)(vbuf + src);
        }
        __syncthreads();
        for (int n = 0; n < 32; ++n) {
            const float* kr = kl + n * 128 + ty * 8;
            const float* vr = vl + n * 128 + tx * 8;
            float4 ka = *(const float4*)(kr),  kb4 = *(const float4*)(kr + 4);
            float4 va = *(const float4*)(vr),  vb4 = *(const float4*)(vr + 4);
            float av[8]  = {ka.x,ka.y,ka.z,ka.w,kb4.x,kb4.y,kb4.z,kb4.w};
            float bvv[8] = {va.x,va.y,va.z,va.w,vb4.x,vb4.y,vb4.z,vb4.w};
#pragma unroll
            for (int i = 0; i < 8; ++i)
#pragma unroll
                for (int j = 0; j < 8; ++j) acc[i][j] += av[i] * bvv[j];
        }
    }
    size_t sbase = ((size_t)(b * 16 + ns)) << 14;
#pragma unroll
    for (int i = 0; i < 8; ++i) {
        int cp = ty * 8 + i;
        *(float4*)(sp + sbase + (cp << 7) + tx * 8)     = make_float4(acc[i][0], acc[i][1], acc[i][2], acc[i][3]);
        *(float4*)(sp + sbase + (cp << 7) + tx * 8 + 4) = make_float4(acc[i][4], acc[i][5], acc[i][6], acc[i][7]);
    }
}

// ---------------- K4bc: reduce 16 partials + fold f_w/BN-scale -> Ttp[b][64][128] ----------------
__global__ __launch_bounds__(256) void k4bc_fold(
    const float* __restrict__ sp, const float* __restrict__ fw,
    const float* __restrict__ fg, const float* __restrict__ fv,
    float* __restrict__ Ttp) {
    __shared__ __align__(16) float sl[32 * 128];   // 16 KB: S rows cp0..cp0+31
    int b = blockIdx.y, g = blockIdx.x;
    int tid = threadIdx.x;
    int cp0 = g << 5;
    for (int i = tid; i < 1024; i += 256) {        // reduce 16 partials
        const float* p = sp + (((size_t)b * 16) << 14) + (size_t)cp0 * 128 + i * 4;
        float4 acc = make_float4(0.f, 0.f, 0.f, 0.f);
#pragma unroll
        for (int q = 0; q < 16; ++q) {
            float4 x = *(const float4*)(p + ((size_t)q << 14));
            acc.x += x.x; acc.y += x.y; acc.z += x.z; acc.w += x.w;
        }
        *(float4*)(sl + i * 4) = acc;
    }
    __syncthreads();
    int cp = tid & 31, orep = tid >> 5;            // 8 o-groups
    const float* sr = sl + cp * 128;
#pragma unroll
    for (int rep = 0; rep < 8; ++rep) {
        int o = orep + (rep << 3);                  // 0..63
        float val = 0.f;
        if (o < 61) {
            float sc = fg[o] * rsqrtf(fv[o] + EPS);
            const float* fwr = fw + o * 122;        // broadcast across the 32 cp-lanes
            float s = 0.f;
            for (int c = 0; c < 122; ++c) s += fwr[c] * sr[c];
            val = sc * s;
        }
        Ttp[((size_t)b * 64 + o) * 128 + cp0 + cp] = val;   // coalesced
    }
}

// ---------------- K5: NT=16 tail: fused = relu(Ttp q + sh) ; c1 ; c2 ; c3 ----------------
__global__ __launch_bounds__(256) void k5_tail(
    const float* __restrict__ qbuf, const float* __restrict__ Ttp,
    const float* __restrict__ fg, const float* __restrict__ fbb,
    const float* __restrict__ fm, const float* __restrict__ fv,
    const float* __restrict__ w1p, const float* __restrict__ bb1,
    const float* __restrict__ w2, const float* __restrict__ bb2,
    const float* __restrict__ w3, const float* __restrict__ bb3,
    float* __restrict__ out) {
    __shared__ __align__(16) float lds[6656];
    const int FUS = 0, H2 = 1024, H1 = 2560;
    int tid = threadIdx.x;
    int b = blockIdx.y;
    int n0 = blockIdx.x << 4;
    int nq = tid & 3, og = tid >> 2;
    // stage QT[cp][n], cp 0..127 (qbuf rows 122..127 are zeros from k3_qkv)
    for (int i = tid; i < 512; i += 256) {
        int n = i >> 5, c4 = i & 31;
        float4 x = *(const float4*)(qbuf + ((size_t)b * 1024 + n0 + n) * 128 + c4 * 4);
        lds[(c4*4+0)*20 + n] = x.x;
        lds[(c4*4+1)*20 + n] = x.y;
        lds[(c4*4+2)*20 + n] = x.z;
        lds[(c4*4+3)*20 + n] = x.w;
    }
    __syncthreads();
    {   // P2': fused[og][n] = relu( sum_cp Ttp[og][cp]*q[cp][n] + sh ), all-float4
        float4 a0 = make_float4(0,0,0,0);
        const float* tb = Ttp + ((size_t)b * 64 + og) * 128;
#pragma unroll 8
        for (int c4 = 0; c4 < 32; ++c4) {
            float4 w  = *(const float4*)(tb + c4 * 4);
            float4 t0 = *(const float4*)(lds + (c4*4+0)*20 + nq*4);
            float4 t1 = *(const float4*)(lds + (c4*4+1)*20 + nq*4);
            float4 t2 = *(const float4*)(lds + (c4*4+2)*20 + nq*4);
            float4 t3 = *(const float4*)(lds + (c4*4+3)*20 + nq*4);
            FMA4(a0, w.x, t0);
            FMA4(a0, w.y, t1);
            FMA4(a0, w.z, t2);
            FMA4(a0, w.w, t3);
        }
        float4 y = make_float4(0.f, 0.f, 0.f, 0.f);
        if (og < 61) {
            float sc = fg[og] * rsqrtf(fv[og] + EPS);
            float sh = fbb[og] - fm[og] * sc;      // scale folded into Ttp
            y.x = fmaxf(a0.x + sh, 0.f); y.y = fmaxf(a0.y + sh, 0.f);
            y.z = fmaxf(a0.z + sh, 0.f); y.w = fmaxf(a0.w + sh, 0.f);
        }
        __syncthreads();   // all QT reads done (FUS overwrites region 0)
        *(float4*)(lds + FUS + og*16 + nq*4) = y;   // rows 61..63 zeroed
        __syncthreads();
    }
    {   // P4: h1[o][n] = relu(c1_w @ fused + c1_b), o = og + 64*i -> H1 (disjoint)
        float4 a[4];
#pragma unroll
        for (int i = 0; i < 4; ++i) a[i] = make_float4(0,0,0,0);
#pragma unroll
        for (int c4 = 0; c4 < 16; ++c4) {
            float4 t0 = *(const float4*)(lds + FUS + (c4*4+0)*16 + nq*4);
            float4 t1 = *(const float4*)(lds + FUS + (c4*4+1)*16 + nq*4);
            float4 t2 = *(const float4*)(lds + FUS + (c4*4+2)*16 + nq*4);
            float4 t3 = *(const float4*)(lds + FUS + (c4*4+3)*16 + nq*4);
#pragma unroll
            for (int i = 0; i < 4; ++i) {
                float4 w = *(const float4*)(w1p + (og + (i<<6)) * 64 + c4 * 4);
                FMA4(a[i], w.x, t0);
                FMA4(a[i], w.y, t1);
                FMA4(a[i], w.z, t2);
                FMA4(a[i], w.w, t3);
            }
        }
#pragma unroll
        for (int i = 0; i < 4; ++i) {
            int o = og + (i<<6);
            float bias = bb1[o];
            float4 y;
            y.x = fmaxf(a[i].x + bias, 0.f); y.y = fmaxf(a[i].y + bias, 0.f);
            y.z = fmaxf(a[i].z + bias, 0.f); y.w = fmaxf(a[i].w + bias, 0.f);
            *(float4*)(lds + H1 + o*16 + nq*4) = y;
        }
        __syncthreads();
    }
    {   // P5: h2[o][n] = relu(c2_w @ h1 + c2_b), o = og -> H2 (disjoint)
        float4 a0 = make_float4(0,0,0,0);
        const float* w2r = w2 + og * 256;
#pragma unroll 8
        for (int c4 = 0; c4 < 64; ++c4) {
            float4 w  = *(const float4*)(w2r + c4 * 4);
            float4 t0 = *(const float4*)(lds + H1 + (c4*4+0)*16 + nq*4);
            float4 t1 = *(const float4*)(lds + H1 + (c4*4+1)*16 + nq*4);
            float4 t2 = *(const float4*)(lds + H1 + (c4*4+2)*16 + nq*4);
            float4 t3 = *(const float4*)(lds + H1 + (c4*4+3)*16 + nq*4);
            FMA4(a0, w.x, t0);
            FMA4(a0, w.y, t1);
            FMA4(a0, w.z, t2);
            FMA4(a0, w.w, t3);
        }
        float ba = bb2[og];
        float4 y;
        y.x = fmaxf(a0.x + ba, 0.f); y.y = fmaxf(a0.y + ba, 0.f);
        y.z = fmaxf(a0.z + ba, 0.f); y.w = fmaxf(a0.w + ba, 0.f);
        *(float4*)(lds + H2 + og*16 + nq*4) = y;
        __syncthreads();
    }
    if (og < 3) {   // P6: sigmoid - 0.5, transposed FP32 store
        float4 a = make_float4(0,0,0,0);
        const float* w3r = w3 + og * 64;
#pragma unroll
        for (int c4 = 0; c4 < 16; ++c4) {
            float4 w  = *(const float4*)(w3r + c4 * 4);
            float4 t0 = *(const float4*)(lds + H2 + (c4*4+0)*16 + nq*4);
            float4 t1 = *(const float4*)(lds + H2 + (c4*4+1)*16 + nq*4);
            float4 t2 = *(const float4*)(lds + H2 + (c4*4+2)*16 + nq*4);
            float4 t3 = *(const float4*)(lds + H2 + (c4*4+3)*16 + nq*4);
            FMA4(a, w.x, t0);
            FMA4(a, w.y, t1);
            FMA4(a, w.z, t2);
            FMA4(a, w.w, t3);
        }
        float bias = bb3[og];
        int nbase = n0 + nq*4;
        out[((size_t)b*1024 + nbase + 0)*3 + og] = 1.f/(1.f+expf(-(a.x+bias))) - 0.5f;
        out[((size_t)b*1024 + nbase + 1)*3 + og] = 1.f/(1.f+expf(-(a.y+bias))) - 0.5f;
        out[((size_t)b*1024 + nbase + 2)*3 + og] = 1.f/(1.f+expf(-(a.z+bias))) - 0.5f;
        out[((size_t)b*1024 + nbase + 3)*3 + og] = 1.f/(1.f+expf(-(a.w+bias))) - 0.5f;
    }
}

extern "C" void kernel_launch(void* const* d_in, const int* in_sizes, int n_in,
                              void* d_out, int out_size, void* d_ws, size_t ws_size,
                              hipStream_t stream) {
    const float* gf      = (const float*)d_in[0];
    const float* token_w = (const float*)d_in[3];
    const float* token_b = (const float*)d_in[4];
    const float* tbn_g   = (const float*)d_in[5];
    const float* tbn_b   = (const float*)d_in[6];
    const float* tbn_m   = (const float*)d_in[7];
    const float* tbn_v   = (const float*)d_in[8];
    const float* q_w = (const float*)d_in[9];
    const float* qg  = (const float*)d_in[10];
    const float* qb  = (const float*)d_in[11];
    const float* qm  = (const float*)d_in[12];
    const float* qv  = (const float*)d_in[13];
    const float* k_w = (const float*)d_in[14];
    const float* kg  = (const float*)d_in[15];
    const float* kb  = (const float*)d_in[16];
    const float* km  = (const float*)d_in[17];
    const float* kv  = (const float*)d_in[18];
    const float* v_w = (const float*)d_in[19];
    const float* vg  = (const float*)d_in[20];
    const float* vb  = (const float*)d_in[21];
    const float* vm  = (const float*)d_in[22];
    const float* vv  = (const float*)d_in[23];
    const float* f_w = (const float*)d_in[24];
    const float* fg  = (const float*)d_in[25];
    const float* fb  = (const float*)d_in[26];
    const float* fm  = (const float*)d_in[27];
    const float* fv  = (const float*)d_in[28];
    const float* c1w = (const float*)d_in[29];
    const float* c1b = (const float*)d_in[30];
    const float* c2w = (const float*)d_in[31];
    const float* c2b = (const float*)d_in[32];
    const float* c3w = (const float*)d_in[33];
    const float* c3b = (const float*)d_in[34];

    float* ws    = (float*)d_ws;
    float* gfeat = ws;                       // 16,384
    float* tok   = gfeat + 16384;            // 2,097,152
    float* kbuf  = tok   + 2097152;          // 4,194,304
    float* vbuf  = kbuf  + 4194304;          // 4,194,304
    float* qbuf  = vbuf  + 4194304;          // 4,194,304
    float* sp    = qbuf  + 4194304;          // 8,388,608
    float* Ttp   = sp    + 8388608;          // 262,144
    float* w1p   = Ttp   + 262144;           // 16,384   -> ~93.4 MB total

    k0_prep   <<<64, 256, 0, stream>>>(c1w, w1p);
    k1_maxpool<<<4096, 256, 0, stream>>>(gf, gfeat);
    k2_token  <<<512, 256, 0, stream>>>(gfeat, token_w, token_b, tbn_g, tbn_b, tbn_m, tbn_v, tok);
    k3_qkv    <<<dim3(16, 32), 384, 0, stream>>>(tok, q_w, k_w, v_w,
                 qg, qb, qm, qv, kg, kb, km, kv, vg, vb, vm, vv, qbuf, kbuf, vbuf);
    k4_s      <<<dim3(16, 32), 256, 0, stream>>>(kbuf, vbuf, sp);
    k4bc_fold <<<dim3(4, 32), 256, 0, stream>>>(sp, f_w, fg, fv, Ttp);
    k5_tail   <<<dim3(64, 32), 256, 0, stream>>>(qbuf, Ttp,
                 fg, fb, fm, fv, w1p, c1b, c2w, c2b, c3w, c3b, (float*)d_out);
}

// Round 17
// 285.389 us; speedup vs baseline: 1.0871x; 1.0871x over previous
//
#include <hip/hip_runtime.h>
#include <float.h>

#define EPS 1e-5f
#define FMA4(A_, W_, T_) { (A_).x += (W_)*(T_).x; (A_).y += (W_)*(T_).y; (A_).z += (W_)*(T_).z; (A_).w += (W_)*(T_).w; }

// ---------------- K0: pad w1 (256x61) -> w1p (256x64, zero-padded cols) ----------------
__global__ __launch_bounds__(256) void k0_prep(const float* __restrict__ w1, float* __restrict__ w1p) {
    int i = blockIdx.x * 256 + threadIdx.x;
    if (i < 16384) {
        int o = i >> 6, c = i & 63;
        w1p[i] = (c < 61) ? w1[o * 61 + c] : 0.f;
    }
}

// ---------------- K1: max over last dim: (32,512,2048) -> (32*512) ----------------
__global__ __launch_bounds__(256) void k1_maxpool(const float* __restrict__ gf, float* __restrict__ gfeat) {
    int row = blockIdx.x * 4 + (threadIdx.x >> 6);   // one wave per row
    int lane = threadIdx.x & 63;
    const float4* p = (const float4*)(gf + (size_t)row * 2048);
    float m = -FLT_MAX;
#pragma unroll
    for (int w = 0; w < 8; ++w) {
        float4 v = p[lane + (w << 6)];
        m = fmaxf(m, fmaxf(fmaxf(v.x, v.y), fmaxf(v.z, v.w)));
    }
#pragma unroll
    for (int off = 32; off >= 1; off >>= 1) m = fmaxf(m, __shfl_xor(m, off));
    if (lane == 0) gfeat[row] = m;
}

// ---------------- K2: tok = relu(bn(gfeat @ token_w^T + token_b)) : (32,65536) ----------------
__global__ __launch_bounds__(256) void k2_token(
    const float* __restrict__ gfeat, const float* __restrict__ tw, const float* __restrict__ tbias,
    const float* __restrict__ bg, const float* __restrict__ bb,
    const float* __restrict__ bm, const float* __restrict__ bv,
    float* __restrict__ tok) {
    __shared__ __align__(16) float wl[128 * 33];
    __shared__ __align__(16) float gl[32 * 36];
    int tid = threadIdx.x;
    int t0 = blockIdx.x * 128;
    int tx = tid & 7, ty = tid >> 3;
    float4 acc[4];
#pragma unroll
    for (int i = 0; i < 4; ++i) acc[i] = make_float4(0.f, 0.f, 0.f, 0.f);
    for (int k0 = 0; k0 < 512; k0 += 32) {
        if (k0) __syncthreads();
        {
            int r = tid >> 1, h = tid & 1;
            const float* src = tw + (size_t)(t0 + r) * 512 + k0 + h * 16;
            float* dst = wl + r * 33 + h * 16;
#pragma unroll
            for (int q = 0; q < 4; ++q) {
                float4 x = *(const float4*)(src + q * 4);
                dst[q*4+0] = x.x; dst[q*4+1] = x.y; dst[q*4+2] = x.z; dst[q*4+3] = x.w;
            }
            int bq = tid >> 3, kq = tid & 7;
            float4 gx = *(const float4*)(gfeat + bq * 512 + k0 + kq * 4);
            gl[(kq*4+0)*36 + bq] = gx.x;
            gl[(kq*4+1)*36 + bq] = gx.y;
            gl[(kq*4+2)*36 + bq] = gx.z;
            gl[(kq*4+3)*36 + bq] = gx.w;
        }
        __syncthreads();
#pragma unroll
        for (int kk = 0; kk < 32; ++kk) {
            float4 g4 = *(const float4*)(gl + kk * 36 + tx * 4);
#pragma unroll
            for (int i = 0; i < 4; ++i) {
                float a = wl[(ty * 4 + i) * 33 + kk];
                FMA4(acc[i], a, g4);
            }
        }
    }
#pragma unroll
    for (int i = 0; i < 4; ++i) {
        int t = t0 + ty * 4 + i;
        float scale = bg[t] * rsqrtf(bv[t] + EPS);
        float sh = (tbias[t] - bm[t]) * scale + bb[t];
        tok[(size_t)(tx*4+0) * 65536 + t] = fmaxf(acc[i].x * scale + sh, 0.f);
        tok[(size_t)(tx*4+1) * 65536 + t] = fmaxf(acc[i].y * scale + sh, 0.f);
        tok[(size_t)(tx*4+2) * 65536 + t] = fmaxf(acc[i].z * scale + sh, 0.f);
        tok[(size_t)(tx*4+3) * 65536 + t] = fmaxf(acc[i].w * scale + sh, 0.f);
    }
}

// ---------------- K3: fused q,k,v projections -> padded [b][n][128] buffers ----------------
// grid (32 ntiles of 32 n, 32 b) = 1024 blocks, 384 threads (6 waves).
// Thread = (m = tid/128 in {q,k,v} — wave-uniform, o = tid&127). 16-float4 weight
// row in regs; processes 4 columns at a time with 4 independent accumulators (ILP).
__global__ __launch_bounds__(384) void k3_qkv(
    const float* __restrict__ tok,
    const float* __restrict__ qw, const float* __restrict__ kw, const float* __restrict__ vw,
    const float* __restrict__ qg, const float* __restrict__ qb, const float* __restrict__ qm, const float* __restrict__ qv,
    const float* __restrict__ kg, const float* __restrict__ kb, const float* __restrict__ km, const float* __restrict__ kvv,
    const float* __restrict__ vg, const float* __restrict__ vb, const float* __restrict__ vm, const float* __restrict__ vvv,
    float* __restrict__ qbuf, float* __restrict__ kbuf, float* __restrict__ vbuf) {
    __shared__ __align__(16) float tokt[32 * 68];    // [n][c], 8.7 KB
    int tid = threadIdx.x;
    int b = blockIdx.y;
    int n0 = blockIdx.x << 5;
    for (int i = tid; i < 512; i += 384) {           // 64 c x 8 quads
        int c = i >> 3, q4 = i & 7;
        float4 x = *(const float4*)(tok + (size_t)b * 65536 + c * 1024 + n0 + q4 * 4);
        tokt[(q4*4+0)*68 + c] = x.x;
        tokt[(q4*4+1)*68 + c] = x.y;
        tokt[(q4*4+2)*68 + c] = x.z;
        tokt[(q4*4+3)*68 + c] = x.w;
    }
    int m = tid / 128;                 // 0:q 1:k 2:v (wave-uniform)
    int o = tid & 127;
    bool valid = (o < 122);
    const float* wsrc = (m == 0) ? qw : ((m == 1) ? kw : vw);
    const float* pg   = (m == 0) ? qg : ((m == 1) ? kg : vg);
    const float* pb   = (m == 0) ? qb : ((m == 1) ? kb : vb);
    const float* pm   = (m == 0) ? qm : ((m == 1) ? km : vm);
    const float* pv   = (m == 0) ? qv : ((m == 1) ? kvv : vvv);
    float* dst        = (m == 0) ? qbuf : ((m == 1) ? kbuf : vbuf);
    float scl = 0.f, shf = 0.f;
    if (valid) {
        float s = pg[o] * rsqrtf(pv[o] + EPS);
        scl = s; shf = pb[o] - pm[o] * s;
    }
    float4 wreg[16];
    {
        const float* wr = wsrc + o * 64;
#pragma unroll
        for (int c4 = 0; c4 < 16; ++c4)
            wreg[c4] = valid ? *(const float4*)(wr + c4 * 4) : make_float4(0.f,0.f,0.f,0.f);
    }
    __syncthreads();
    for (int nn0 = 0; nn0 < 32; nn0 += 4) {          // 4 independent chains per iter
        const float* t0 = tokt + (nn0+0) * 68;
        const float* t1 = tokt + (nn0+1) * 68;
        const float* t2 = tokt + (nn0+2) * 68;
        const float* t3 = tokt + (nn0+3) * 68;
        float s0 = 0.f, s1 = 0.f, s2 = 0.f, s3 = 0.f;
#pragma unroll
        for (int c4 = 0; c4 < 16; ++c4) {
            float4 w = wreg[c4];
            float4 a = *(const float4*)(t0 + c4 * 4);
            float4 bq = *(const float4*)(t1 + c4 * 4);
            float4 c = *(const float4*)(t2 + c4 * 4);
            float4 d = *(const float4*)(t3 + c4 * 4);
            s0 += w.x*a.x + w.y*a.y + w.z*a.z + w.w*a.w;
            s1 += w.x*bq.x + w.y*bq.y + w.z*bq.z + w.w*bq.w;
            s2 += w.x*c.x + w.y*c.y + w.z*c.z + w.w*c.w;
            s3 += w.x*d.x + w.y*d.y + w.z*d.z + w.w*d.w;
        }
        size_t base = ((size_t)b * 1024 + n0 + nn0) * 128 + o;
        dst[base +   0] = fmaxf(s0 * scl + shf, 0.f);
        dst[base + 128] = fmaxf(s1 * scl + shf, 0.f);
        dst[base + 256] = fmaxf(s2 * scl + shf, 0.f);
        dst[base + 384] = fmaxf(s3 * scl + shf, 0.f);
    }
}

// ---------------- K4: S partials — pure outer-product GEMM over n ----------------
__global__ __launch_bounds__(256) void k4_s(
    const float* __restrict__ kbuf, const float* __restrict__ vbuf,
    float* __restrict__ sp) {
    __shared__ __align__(16) float kl[32 * 128];
    __shared__ __align__(16) float vl[32 * 128];
    int tid = threadIdx.x;
    int b = blockIdx.y, ns = blockIdx.x;
    int tx = tid & 15, ty = tid >> 4;
    float acc[8][8];
#pragma unroll
    for (int i = 0; i < 8; ++i)
#pragma unroll
        for (int j = 0; j < 8; ++j) acc[i][j] = 0.f;
    for (int chunk = 0; chunk < 2; ++chunk) {
        int nb = (ns << 6) + (chunk << 5);
        if (chunk) __syncthreads();
        for (int i = tid; i < 1024; i += 256) {
            int n = i >> 5, q = i & 31;
            size_t src = ((size_t)b * 1024 + nb + n) * 128 + q * 4;
            *(float4*)(kl + n * 128 + q * 4) = *(const float4*)(kbuf + src);
            *(float4*)(vl + n * 128 + q * 4) = *(const float4*)(vbuf + src);
        }
        __syncthreads();
        for (int n = 0; n < 32; ++n) {
            const float* kr = kl + n * 128 + ty * 8;
            const float* vr = vl + n * 128 + tx * 8;
            float4 ka = *(const float4*)(kr),  kb4 = *(const float4*)(kr + 4);
            float4 va = *(const float4*)(vr),  vb4 = *(const float4*)(vr + 4);
            float av[8]  = {ka.x,ka.y,ka.z,ka.w,kb4.x,kb4.y,kb4.z,kb4.w};
            float bvv[8] = {va.x,va.y,va.z,va.w,vb4.x,vb4.y,vb4.z,vb4.w};
#pragma unroll
            for (int i = 0; i < 8; ++i)
#pragma unroll
                for (int j = 0; j < 8; ++j) acc[i][j] += av[i] * bvv[j];
        }
    }
    size_t sbase = ((size_t)(b * 16 + ns)) << 14;
#pragma unroll
    for (int i = 0; i < 8; ++i) {
        int cp = ty * 8 + i;
        *(float4*)(sp + sbase + (cp << 7) + tx * 8)     = make_float4(acc[i][0], acc[i][1], acc[i][2], acc[i][3]);
        *(float4*)(sp + sbase + (cp << 7) + tx * 8 + 4) = make_float4(acc[i][4], acc[i][5], acc[i][6], acc[i][7]);
    }
}

// ---------------- K4bc: reduce 16 partials + fold f_w/BN-scale -> Ttp[b][64][128] ----------------
__global__ __launch_bounds__(256) void k4bc_fold(
    const float* __restrict__ sp, const float* __restrict__ fw,
    const float* __restrict__ fg, const float* __restrict__ fv,
    float* __restrict__ Ttp) {
    __shared__ __align__(16) float sl[32 * 128];   // 16 KB: S rows cp0..cp0+31
    int b = blockIdx.y, g = blockIdx.x;
    int tid = threadIdx.x;
    int cp0 = g << 5;
    for (int i = tid; i < 1024; i += 256) {        // reduce 16 partials
        const float* p = sp + (((size_t)b * 16) << 14) + (size_t)cp0 * 128 + i * 4;
        float4 acc = make_float4(0.f, 0.f, 0.f, 0.f);
#pragma unroll
        for (int q = 0; q < 16; ++q) {
            float4 x = *(const float4*)(p + ((size_t)q << 14));
            acc.x += x.x; acc.y += x.y; acc.z += x.z; acc.w += x.w;
        }
        *(float4*)(sl + i * 4) = acc;
    }
    __syncthreads();
    int cp = tid & 31, orep = tid >> 5;            // 8 o-groups
    const float* sr = sl + cp * 128;
#pragma unroll
    for (int rep = 0; rep < 8; ++rep) {
        int o = orep + (rep << 3);                  // 0..63
        float val = 0.f;
        if (o < 61) {
            float sc = fg[o] * rsqrtf(fv[o] + EPS);
            const float* fwr = fw + o * 122;        // broadcast across the 32 cp-lanes
            float s = 0.f;
            for (int c = 0; c < 122; ++c) s += fwr[c] * sr[c];
            val = sc * s;
        }
        Ttp[((size_t)b * 64 + o) * 128 + cp0 + cp] = val;   // coalesced
    }
}

// ---------------- K5: NT=16 tail: fused = relu(Ttp q + sh) ; c1 ; c2 ; c3 ----------------
__global__ __launch_bounds__(256) void k5_tail(
    const float* __restrict__ qbuf, const float* __restrict__ Ttp,
    const float* __restrict__ fg, const float* __restrict__ fbb,
    const float* __restrict__ fm, const float* __restrict__ fv,
    const float* __restrict__ w1p, const float* __restrict__ bb1,
    const float* __restrict__ w2, const float* __restrict__ bb2,
    const float* __restrict__ w3, const float* __restrict__ bb3,
    float* __restrict__ out) {
    __shared__ __align__(16) float lds[6656];
    const int FUS = 0, H2 = 1024, H1 = 2560;
    int tid = threadIdx.x;
    int b = blockIdx.y;
    int n0 = blockIdx.x << 4;
    int nq = tid & 3, og = tid >> 2;
    // stage QT[cp][n], cp 0..127 (qbuf rows 122..127 are zeros from k3_qkv)
    for (int i = tid; i < 512; i += 256) {
        int n = i >> 5, c4 = i & 31;
        float4 x = *(const float4*)(qbuf + ((size_t)b * 1024 + n0 + n) * 128 + c4 * 4);
        lds[(c4*4+0)*20 + n] = x.x;
        lds[(c4*4+1)*20 + n] = x.y;
        lds[(c4*4+2)*20 + n] = x.z;
        lds[(c4*4+3)*20 + n] = x.w;
    }
    __syncthreads();
    {   // P2': fused[og][n] = relu( sum_cp Ttp[og][cp]*q[cp][n] + sh ), all-float4
        float4 a0 = make_float4(0,0,0,0);
        const float* tb = Ttp + ((size_t)b * 64 + og) * 128;
#pragma unroll 8
        for (int c4 = 0; c4 < 32; ++c4) {
            float4 w  = *(const float4*)(tb + c4 * 4);
            float4 t0 = *(const float4*)(lds + (c4*4+0)*20 + nq*4);
            float4 t1 = *(const float4*)(lds + (c4*4+1)*20 + nq*4);
            float4 t2 = *(const float4*)(lds + (c4*4+2)*20 + nq*4);
            float4 t3 = *(const float4*)(lds + (c4*4+3)*20 + nq*4);
            FMA4(a0, w.x, t0);
            FMA4(a0, w.y, t1);
            FMA4(a0, w.z, t2);
            FMA4(a0, w.w, t3);
        }
        float4 y = make_float4(0.f, 0.f, 0.f, 0.f);
        if (og < 61) {
            float sc = fg[og] * rsqrtf(fv[og] + EPS);
            float sh = fbb[og] - fm[og] * sc;      // scale folded into Ttp
            y.x = fmaxf(a0.x + sh, 0.f); y.y = fmaxf(a0.y + sh, 0.f);
            y.z = fmaxf(a0.z + sh, 0.f); y.w = fmaxf(a0.w + sh, 0.f);
        }
        __syncthreads();   // all QT reads done (FUS overwrites region 0)
        *(float4*)(lds + FUS + og*16 + nq*4) = y;   // rows 61..63 zeroed
        __syncthreads();
    }
    {   // P4: h1[o][n] = relu(c1_w @ fused + c1_b), o = og + 64*i -> H1 (disjoint)
        float4 a[4];
#pragma unroll
        for (int i = 0; i < 4; ++i) a[i] = make_float4(0,0,0,0);
#pragma unroll
        for (int c4 = 0; c4 < 16; ++c4) {
            float4 t0 = *(const float4*)(lds + FUS + (c4*4+0)*16 + nq*4);
            float4 t1 = *(const float4*)(lds + FUS + (c4*4+1)*16 + nq*4);
            float4 t2 = *(const float4*)(lds + FUS + (c4*4+2)*16 + nq*4);
            float4 t3 = *(const float4*)(lds + FUS + (c4*4+3)*16 + nq*4);
#pragma unroll
            for (int i = 0; i < 4; ++i) {
                float4 w = *(const float4*)(w1p + (og + (i<<6)) * 64 + c4 * 4);
                FMA4(a[i], w.x, t0);
                FMA4(a[i], w.y, t1);
                FMA4(a[i], w.z, t2);
                FMA4(a[i], w.w, t3);
            }
        }
#pragma unroll
        for (int i = 0; i < 4; ++i) {
            int o = og + (i<<6);
            float bias = bb1[o];
            float4 y;
            y.x = fmaxf(a[i].x + bias, 0.f); y.y = fmaxf(a[i].y + bias, 0.f);
            y.z = fmaxf(a[i].z + bias, 0.f); y.w = fmaxf(a[i].w + bias, 0.f);
            *(float4*)(lds + H1 + o*16 + nq*4) = y;
        }
        __syncthreads();
    }
    {   // P5: h2[o][n] = relu(c2_w @ h1 + c2_b), o = og -> H2 (disjoint)
        float4 a0 = make_float4(0,0,0,0);
        const float* w2r = w2 + og * 256;
#pragma unroll 8
        for (int c4 = 0; c4 < 64; ++c4) {
            float4 w  = *(const float4*)(w2r + c4 * 4);
            float4 t0 = *(const float4*)(lds + H1 + (c4*4+0)*16 + nq*4);
            float4 t1 = *(const float4*)(lds + H1 + (c4*4+1)*16 + nq*4);
            float4 t2 = *(const float4*)(lds + H1 + (c4*4+2)*16 + nq*4);
            float4 t3 = *(const float4*)(lds + H1 + (c4*4+3)*16 + nq*4);
            FMA4(a0, w.x, t0);
            FMA4(a0, w.y, t1);
            FMA4(a0, w.z, t2);
            FMA4(a0, w.w, t3);
        }
        float ba = bb2[og];
        float4 y;
        y.x = fmaxf(a0.x + ba, 0.f); y.y = fmaxf(a0.y + ba, 0.f);
        y.z = fmaxf(a0.z + ba, 0.f); y.w = fmaxf(a0.w + ba, 0.f);
        *(float4*)(lds + H2 + og*16 + nq*4) = y;
        __syncthreads();
    }
    if (og < 3) {   // P6: sigmoid - 0.5, transposed FP32 store
        float4 a = make_float4(0,0,0,0);
        const float* w3r = w3 + og * 64;
#pragma unroll
        for (int c4 = 0; c4 < 16; ++c4) {
            float4 w  = *(const float4*)(w3r + c4 * 4);
            float4 t0 = *(const float4*)(lds + H2 + (c4*4+0)*16 + nq*4);
            float4 t1 = *(const float4*)(lds + H2 + (c4*4+1)*16 + nq*4);
            float4 t2 = *(const float4*)(lds + H2 + (c4*4+2)*16 + nq*4);
            float4 t3 = *(const float4*)(lds + H2 + (c4*4+3)*16 + nq*4);
            FMA4(a, w.x, t0);
            FMA4(a, w.y, t1);
            FMA4(a, w.z, t2);
            FMA4(a, w.w, t3);
        }
        float bias = bb3[og];
        int nbase = n0 + nq*4;
        out[((size_t)b*1024 + nbase + 0)*3 + og] = 1.f/(1.f+expf(-(a.x+bias))) - 0.5f;
        out[((size_t)b*1024 + nbase + 1)*3 + og] = 1.f/(1.f+expf(-(a.y+bias))) - 0.5f;
        out[((size_t)b*1024 + nbase + 2)*3 + og] = 1.f/(1.f+expf(-(a.z+bias))) - 0.5f;
        out[((size_t)b*1024 + nbase + 3)*3 + og] = 1.f/(1.f+expf(-(a.w+bias))) - 0.5f;
    }
}

extern "C" void kernel_launch(void* const* d_in, const int* in_sizes, int n_in,
                              void* d_out, int out_size, void* d_ws, size_t ws_size,
                              hipStream_t stream) {
    const float* gf      = (const float*)d_in[0];
    const float* token_w = (const float*)d_in[3];
    const float* token_b = (const float*)d_in[4];
    const float* tbn_g   = (const float*)d_in[5];
    const float* tbn_b   = (const float*)d_in[6];
    const float* tbn_m   = (const float*)d_in[7];
    const float* tbn_v   = (const float*)d_in[8];
    const float* q_w = (const float*)d_in[9];
    const float* qg  = (const float*)d_in[10];
    const float* qb  = (const float*)d_in[11];
    const float* qm  = (const float*)d_in[12];
    const float* qv  = (const float*)d_in[13];
    const float* k_w = (const float*)d_in[14];
    const float* kg  = (const float*)d_in[15];
    const float* kb  = (const float*)d_in[16];
    const float* km  = (const float*)d_in[17];
    const float* kv  = (const float*)d_in[18];
    const float* v_w = (const float*)d_in[19];
    const float* vg  = (const float*)d_in[20];
    const float* vb  = (const float*)d_in[21];
    const float* vm  = (const float*)d_in[22];
    const float* vv  = (const float*)d_in[23];
    const float* f_w = (const float*)d_in[24];
    const float* fg  = (const float*)d_in[25];
    const float* fb  = (const float*)d_in[26];
    const float* fm  = (const float*)d_in[27];
    const float* fv  = (const float*)d_in[28];
    const float* c1w = (const float*)d_in[29];
    const float* c1b = (const float*)d_in[30];
    const float* c2w = (const float*)d_in[31];
    const float* c2b = (const float*)d_in[32];
    const float* c3w = (const float*)d_in[33];
    const float* c3b = (const float*)d_in[34];

    float* ws    = (float*)d_ws;
    float* gfeat = ws;                       // 16,384
    float* tok   = gfeat + 16384;            // 2,097,152
    float* kbuf  = tok   + 2097152;          // 4,194,304
    float* vbuf  = kbuf  + 4194304;          // 4,194,304
    float* qbuf  = vbuf  + 4194304;          // 4,194,304
    float* sp    = qbuf  + 4194304;          // 8,388,608
    float* Ttp   = sp    + 8388608;          // 262,144
    float* w1p   = Ttp   + 262144;           // 16,384   -> ~93.4 MB total

    k0_prep   <<<64, 256, 0, stream>>>(c1w, w1p);
    k1_maxpool<<<4096, 256, 0, stream>>>(gf, gfeat);
    k2_token  <<<512, 256, 0, stream>>>(gfeat, token_w, token_b, tbn_g, tbn_b, tbn_m, tbn_v, tok);
    k3_qkv    <<<dim3(32, 32), 384, 0, stream>>>(tok, q_w, k_w, v_w,
                 qg, qb, qm, qv, kg, kb, km, kv, vg, vb, vm, vv, qbuf, kbuf, vbuf);
    k4_s      <<<dim3(16, 32), 256, 0, stream>>>(kbuf, vbuf, sp);
    k4bc_fold <<<dim3(4, 32), 256, 0, stream>>>(sp, f_w, fg, fv, Ttp);
    k5_tail   <<<dim3(64, 32), 256, 0, stream>>>(qbuf, Ttp,
                 fg, fb, fm, fv, w1p, c1b, c2w, c2b, c3w, c3b, (float*)d_out);
}